// Round 7
// baseline (411.003 us; speedup 1.0000x reference)
//
#include <hip/hip_runtime.h>
#include <hip/hip_bf16.h>
#include <stdint.h>

#define NT 2048
#define DM 1024
#define DFF 2048
#define NE 8
#define NASSIGN (NT*2)
#define CAPROWS (NASSIGN+128)
#define MAXTILES 40
#define BK 32   // k-chunk per LDS tile, in ushorts (64B rows)

typedef __attribute__((ext_vector_type(4))) float f32x4;
typedef __attribute__((ext_vector_type(8))) short bf16x8;

// async global->LDS, 16B per lane; LDS dest = wave-uniform base + lane*16
#define GLOAD16(gptr, lptr) __builtin_amdgcn_global_load_lds( \
    (const __attribute__((address_space(1))) void*)(gptr), \
    (__attribute__((address_space(3))) void*)(lptr), 16, 0, 0)

__device__ __forceinline__ ushort f2bf(float f) {
  union { float f; uint32_t u; } v; v.f = f;
  uint32_t u = v.u;
  return (ushort)((u + 0x7FFFu + ((u >> 16) & 1u)) >> 16);
}

// ---------------- router: one wave per token (no atomics) ----------------
__global__ __launch_bounds__(256) void k_router(const float* __restrict__ x,
    const float* __restrict__ rw, int* __restrict__ tok_e, float* __restrict__ tok_p) {
  __shared__ float srw[NE*DM];
  int tid = threadIdx.x;
  #pragma unroll
  for (int i = 0; i < NE*DM/256; i++) srw[tid + i*256] = rw[tid + i*256];
  __syncthreads();
  int lane = tid & 63;
  int t = blockIdx.x*4 + (tid >> 6);
  const float* xr = x + (size_t)t*DM;
  float acc[NE];
  #pragma unroll
  for (int e = 0; e < NE; e++) acc[e] = 0.f;
  for (int i = lane; i < DM; i += 64) {
    float xv = xr[i];
    #pragma unroll
    for (int e = 0; e < NE; e++) acc[e] = fmaf(xv, srw[e*DM + i], acc[e]);
  }
  #pragma unroll
  for (int e = 0; e < NE; e++) {
    float v = acc[e];
    #pragma unroll
    for (int o = 32; o > 0; o >>= 1) v += __shfl_xor(v, o);
    acc[e] = v;
  }
  float mx = acc[0];
  #pragma unroll
  for (int e = 1; e < NE; e++) mx = fmaxf(mx, acc[e]);
  float p[NE]; float s = 0.f;
  #pragma unroll
  for (int e = 0; e < NE; e++) { p[e] = __expf(acc[e]-mx); s += p[e]; }
  int e1 = 0; float b1 = p[0];
  #pragma unroll
  for (int e = 1; e < NE; e++) if (p[e] > b1) { b1 = p[e]; e1 = e; }
  int e2 = -1; float b2 = -1.f;
  #pragma unroll
  for (int e = 0; e < NE; e++) if (e != e1 && p[e] > b2) { b2 = p[e]; e2 = e; }
  if (lane == 0) {
    tok_e[2*t] = e1; tok_e[2*t+1] = e2;
    float inv = 1.f/s;
    tok_p[2*t] = b1*inv; tok_p[2*t+1] = b2*inv;
  }
}

// ---------------- count: deterministic within-chunk ranks, no atomics -------
__global__ __launch_bounds__(256) void k_count(const int* __restrict__ tok_e,
    int* __restrict__ rnk, int* __restrict__ chunk_cnt) {
  __shared__ int wcnt[4][NE];
  __shared__ int woff[4][NE];
  int tid = threadIdx.x, lane = tid & 63, wv = tid >> 6;
  int t = blockIdx.x*256 + tid;
  int e1 = tok_e[2*t], e2 = tok_e[2*t+1];
  unsigned long long lt = (lane == 63) ? 0x7FFFFFFFFFFFFFFFull
                                       : ((1ull << lane) - 1ull);
  int r0 = 0, r1 = 0;
  #pragma unroll
  for (int e = 0; e < NE; e++) {
    unsigned long long m0 = __ballot(e1 == e);
    unsigned long long m1 = __ballot(e2 == e);
    if (e1 == e) r0 = __popcll(m0 & lt) + __popcll(m1 & lt);
    if (e2 == e) r1 = __popcll(m0 & lt) + (int)(e1 == e) + __popcll(m1 & lt);
    if (lane == 0) wcnt[wv][e] = __popcll(m0) + __popcll(m1);
  }
  __syncthreads();
  if (tid < NE) {
    int s = 0;
    #pragma unroll
    for (int w = 0; w < 4; w++) { woff[w][tid] = s; s += wcnt[w][tid]; }
    chunk_cnt[blockIdx.x*NE + tid] = s;
  }
  __syncthreads();
  rnk[2*t]   = woff[wv][e1] + r0;
  rnk[2*t+1] = woff[wv][e2] + r1;
}

// ---------------- scan: expert offsets, chunk offsets, tile descriptors -----
__global__ void k_scan(const int* __restrict__ chunk_cnt, int* __restrict__ offs,
    int* __restrict__ coff, int* __restrict__ d_e, int* __restrict__ d_r0,
    int* __restrict__ d_valid, int* __restrict__ ntiles) {
  if (threadIdx.x == 0 && blockIdx.x == 0) {
    int cnt[NE];
    for (int e = 0; e < NE; e++) {
      int s = 0;
      for (int c = 0; c < 8; c++) s += chunk_cnt[c*NE + e];
      cnt[e] = s;
    }
    int off = 0, nt2 = 0;
    for (int e = 0; e < NE; e++) {
      offs[e] = off;
      int s = off;
      for (int c = 0; c < 8; c++) { coff[c*NE + e] = s; s += chunk_cnt[c*NE + e]; }
      for (int r = 0; r < cnt[e]; r += 128) {
        d_e[nt2] = e; d_r0[nt2] = off + r;
        d_valid[nt2] = (cnt[e] - r < 128) ? (cnt[e] - r) : 128;
        nt2++;
      }
      off += cnt[e];
    }
    *ntiles = nt2;
  }
}

// ---------------- gather: xg[slot] = bf16(p * x[token]), no atomics ---------
__global__ __launch_bounds__(256) void k_gather(const float* __restrict__ x,
    const int* __restrict__ tok_e, const float* __restrict__ tok_p,
    const int* __restrict__ rnk, const int* __restrict__ coff,
    int* __restrict__ assign_token, ushort* __restrict__ xg) {
  int tid = threadIdx.x, lane = tid & 63;
  int t = blockIdx.x*4 + (tid >> 6);
  const float* xr = x + (size_t)t*DM;
  int chunk = t >> 8;
  #pragma unroll
  for (int j = 0; j < 2; j++) {
    int e = tok_e[2*t+j];
    float pp = tok_p[2*t+j];
    int slot = coff[chunk*NE + e] + rnk[2*t+j];
    if (lane == 0) assign_token[slot] = t;
    ushort* dst = xg + (size_t)slot*DM;
    #pragma unroll
    for (int it = 0; it < 2; it++) {
      int c = lane + it*64;
      float4 v0 = *(const float4*)(xr + c*8);
      float4 v1 = *(const float4*)(xr + c*8 + 4);
      uint4 o;
      o.x = (uint32_t)f2bf(v0.x*pp) | ((uint32_t)f2bf(v0.y*pp) << 16);
      o.y = (uint32_t)f2bf(v0.z*pp) | ((uint32_t)f2bf(v0.w*pp) << 16);
      o.z = (uint32_t)f2bf(v1.x*pp) | ((uint32_t)f2bf(v1.y*pp) << 16);
      o.w = (uint32_t)f2bf(v1.z*pp) | ((uint32_t)f2bf(v1.w*pp) << 16);
      *(uint4*)(dst + c*8) = o;
    }
  }
}

// ---------------- transpose: src [E][K][N] f32 -> dst [E][N][K] bf16 --------
__global__ __launch_bounds__(256) void k_transpose(const float* __restrict__ src,
    ushort* __restrict__ dst, int K, int N) {
  __shared__ ushort tl[64][68];
  int e = blockIdx.z;
  const float* s = src + (size_t)e*K*N;
  ushort* d = dst + (size_t)e*N*K;
  int n0 = blockIdx.x*64, k0 = blockIdx.y*64;
  int tid = threadIdx.x;
  int cx = tid & 15, ry = tid >> 4;
  #pragma unroll
  for (int p = 0; p < 4; p++) {
    int k = k0 + ry + p*16;
    float4 v = *(const float4*)(s + (size_t)k*N + n0 + cx*4);
    tl[cx*4+0][ry+p*16] = f2bf(v.x);
    tl[cx*4+1][ry+p*16] = f2bf(v.y);
    tl[cx*4+2][ry+p*16] = f2bf(v.z);
    tl[cx*4+3][ry+p*16] = f2bf(v.w);
  }
  __syncthreads();
  #pragma unroll
  for (int p = 0; p < 4; p++) {
    int n = ry + p*16;
    ushort* dp = d + (size_t)(n0+n)*K + k0 + cx*4;
    uint2 o;
    o.x = (uint32_t)tl[n][cx*4+0] | ((uint32_t)tl[n][cx*4+1] << 16);
    o.y = (uint32_t)tl[n][cx*4+2] | ((uint32_t)tl[n][cx*4+3] << 16);
    *(uint2*)dp = o;
  }
}

// ---- fused gate+up GEMM: 128(M)x64(N) tile, BK=32, global_load_lds,
//      XOR-swizzled LDS, 2-phase double-buffer (stage next || compute cur) ---
__global__ __launch_bounds__(256) void k_gemm_gu(
    const ushort* __restrict__ Abuf, const ushort* __restrict__ Bbuf,
    ushort* __restrict__ hidden,
    const int* __restrict__ d_e, const int* __restrict__ d_r0,
    const int* __restrict__ d_valid, const int* __restrict__ ntiles) {
  if (blockIdx.y >= *ntiles) return;
  const int K = DM;
  const int e     = d_e[blockIdx.y];
  const int row0  = d_r0[blockIdx.y];
  const int valid = d_valid[blockIdx.y];
  const int n0 = blockIdx.x * 64;

  __shared__ __align__(16) ushort As [2*128*BK];  // 16KB (2 bufs)
  __shared__ __align__(16) ushort Bgs[2* 64*BK];  //  8KB
  __shared__ __align__(16) ushort Bus[2* 64*BK];  //  8KB

  int tid = threadIdx.x;
  int lane = tid & 63;
  int wv = tid >> 6;
  int wm = wv >> 1, wn = wv & 1;

  const ushort* Ab  = Abuf + (size_t)row0 * K;
  const ushort* Bgb = Bbuf + ((size_t)e*4096 + n0) * K;
  const ushort* Bub = Bbuf + ((size_t)e*4096 + 2048 + n0) * K;

  // staging: phys row = tid>>2, phys chunk = tid&3; source fetches LOGICAL
  // chunk c = (tid&3) ^ ((row>>1)&3) = (tid&3) ^ ((tid>>3)&3)   (lane-only)
  int sr  = tid >> 2;
  int sc8 = (((tid & 3) ^ ((tid >> 3) & 3))) * 8;
  const ushort* Ag0 = Ab  + (size_t)sr*K + sc8;
  const ushort* Ag1 = Ab  + (size_t)(sr+64)*K + sc8;
  const ushort* Gg0 = Bgb + (size_t)sr*K + sc8;
  const ushort* Ug0 = Bub + (size_t)sr*K + sc8;

#define STAGE_GU(b, kofs) do { \
    GLOAD16(Ag0 + (kofs), As  + (b)*4096 + wv*512); \
    GLOAD16(Ag1 + (kofs), As  + (b)*4096 + 2048 + wv*512); \
    GLOAD16(Gg0 + (kofs), Bgs + (b)*2048 + wv*512); \
    GLOAD16(Ug0 + (kofs), Bus + (b)*2048 + wv*512); \
  } while (0)

  f32x4 accg[4][2], accu[4][2];
  f32x4 zz = {0.f, 0.f, 0.f, 0.f};
  #pragma unroll
  for (int mi = 0; mi < 4; mi++)
    #pragma unroll
    for (int ni = 0; ni < 2; ni++) { accg[mi][ni] = zz; accu[mi][ni] = zz; }

  // read side: logical chunk lane>>4 of row (..+lane&15) is at phys chunk
  // p = (lane>>4) ^ ((lane>>1)&3); per-lane constant offset:
  int roff = (lane & 15)*BK + ((lane >> 4) ^ ((lane >> 1) & 3))*8;

  const int NK = K / BK;
  STAGE_GU(0, 0);
  __syncthreads();                       // vmcnt(0): buf0 ready
  for (int kt = 0; kt < NK; kt++) {
    int cur = kt & 1;
    if (kt + 1 < NK) STAGE_GU(cur ^ 1, (kt + 1) * BK);   // loads fly under compute

    const ushort* Ap = As  + cur*4096;
    const ushort* Gp = Bgs + cur*2048;
    const ushort* Up = Bus + cur*2048;
    bf16x8 af[4], bg[2], bu[2];
    #pragma unroll
    for (int mi = 0; mi < 4; mi++)
      af[mi] = *(const bf16x8*)(Ap + (wm*64 + mi*16)*BK + roff);
    #pragma unroll
    for (int ni = 0; ni < 2; ni++) {
      bg[ni] = *(const bf16x8*)(Gp + (wn*32 + ni*16)*BK + roff);
      bu[ni] = *(const bf16x8*)(Up + (wn*32 + ni*16)*BK + roff);
    }
    #pragma unroll
    for (int mi = 0; mi < 4; mi++)
      #pragma unroll
      for (int ni = 0; ni < 2; ni++) {
        accg[mi][ni] = __builtin_amdgcn_mfma_f32_16x16x32_bf16(af[mi], bg[ni], accg[mi][ni], 0, 0, 0);
        accu[mi][ni] = __builtin_amdgcn_mfma_f32_16x16x32_bf16(af[mi], bu[ni], accu[mi][ni], 0, 0, 0);
      }
    __syncthreads();                     // vmcnt(0)+lgkmcnt(0): next buf ready, cur drained
  }
#undef STAGE_GU

  #pragma unroll
  for (int mi = 0; mi < 4; mi++) {
    #pragma unroll
    for (int r = 0; r < 4; r++) {
      int row_l = wm*64 + mi*16 + (lane>>4)*4 + r;
      if (row_l < valid) {
        #pragma unroll
        for (int ni = 0; ni < 2; ni++) {
          int col = n0 + wn*32 + ni*16 + (lane&15);
          float g = accg[mi][ni][r];
          g = fminf(fmaxf(g, -10.f), 10.f);
          float sg = g / (1.f + __expf(-g));
          float h = sg * accu[mi][ni][r];
          hidden[(size_t)(row0+row_l)*DFF + col] = f2bf(h);
        }
      }
    }
  }
}

// ---- down GEMM: 128(M)x64(N) tile, BK=32, gload_lds, swizzle, 2-phase dbuf -
// out[token] += hidden_tile @ dnt
__global__ __launch_bounds__(256) void k_gemm_dn(
    const ushort* __restrict__ Abuf, const ushort* __restrict__ Bbuf,
    float* __restrict__ out,
    const int* __restrict__ d_e, const int* __restrict__ d_r0,
    const int* __restrict__ d_valid, const int* __restrict__ ntiles,
    const int* __restrict__ assign_token) {
  if (blockIdx.y >= *ntiles) return;
  const int K = DFF;
  const int e     = d_e[blockIdx.y];
  const int row0  = d_r0[blockIdx.y];
  const int valid = d_valid[blockIdx.y];
  const int n0 = blockIdx.x * 64;

  __shared__ __align__(16) ushort As[2*128*BK];  // 16KB
  __shared__ __align__(16) ushort Bs[2* 64*BK];  //  8KB
  __shared__ int toks[128];

  int tid = threadIdx.x;
  int lane = tid & 63;
  int wv = tid >> 6;
  int wm = wv >> 1, wn = wv & 1;

  const ushort* Ab = Abuf + (size_t)row0 * K;
  const ushort* Bb = Bbuf + ((size_t)e*1024 + n0) * K;
  if (tid < 128) toks[tid] = assign_token[row0 + tid];

  int sr  = tid >> 2;
  int sc8 = (((tid & 3) ^ ((tid >> 3) & 3))) * 8;
  const ushort* Ag0 = Ab + (size_t)sr*K + sc8;
  const ushort* Ag1 = Ab + (size_t)(sr+64)*K + sc8;
  const ushort* Bg0 = Bb + (size_t)sr*K + sc8;

#define STAGE_DN(b, kofs) do { \
    GLOAD16(Ag0 + (kofs), As + (b)*4096 + wv*512); \
    GLOAD16(Ag1 + (kofs), As + (b)*4096 + 2048 + wv*512); \
    GLOAD16(Bg0 + (kofs), Bs + (b)*2048 + wv*512); \
  } while (0)

  f32x4 acc[4][2];
  f32x4 zz = {0.f, 0.f, 0.f, 0.f};
  #pragma unroll
  for (int mi = 0; mi < 4; mi++)
    #pragma unroll
    for (int ni = 0; ni < 2; ni++) acc[mi][ni] = zz;

  int roff = (lane & 15)*BK + ((lane >> 4) ^ ((lane >> 1) & 3))*8;

  const int NK = K / BK;
  STAGE_DN(0, 0);
  __syncthreads();
  for (int kt = 0; kt < NK; kt++) {
    int cur = kt & 1;
    if (kt + 1 < NK) STAGE_DN(cur ^ 1, (kt + 1) * BK);

    const ushort* Ap = As + cur*4096;
    const ushort* Bp = Bs + cur*2048;
    bf16x8 af[4], bfr[2];
    #pragma unroll
    for (int mi = 0; mi < 4; mi++)
      af[mi] = *(const bf16x8*)(Ap + (wm*64 + mi*16)*BK + roff);
    #pragma unroll
    for (int ni = 0; ni < 2; ni++)
      bfr[ni] = *(const bf16x8*)(Bp + (wn*32 + ni*16)*BK + roff);
    #pragma unroll
    for (int mi = 0; mi < 4; mi++)
      #pragma unroll
      for (int ni = 0; ni < 2; ni++)
        acc[mi][ni] = __builtin_amdgcn_mfma_f32_16x16x32_bf16(af[mi], bfr[ni], acc[mi][ni], 0, 0, 0);
    __syncthreads();
  }
#undef STAGE_DN

  #pragma unroll
  for (int mi = 0; mi < 4; mi++) {
    #pragma unroll
    for (int r = 0; r < 4; r++) {
      int row_l = wm*64 + mi*16 + (lane>>4)*4 + r;
      if (row_l < valid) {
        #pragma unroll
        for (int ni = 0; ni < 2; ni++) {
          int col = n0 + wn*32 + ni*16 + (lane&15);
          atomicAdd(out + (size_t)toks[row_l]*DM + col, acc[mi][ni][r]);
        }
      }
    }
  }
}

// ---------------- launch ----------------
extern "C" void kernel_launch(void* const* d_in, const int* in_sizes, int n_in,
                              void* d_out, int out_size, void* d_ws, size_t ws_size,
                              hipStream_t stream) {
  const float* x   = (const float*)d_in[0];
  const float* rw  = (const float*)d_in[1];
  const float* guw = (const float*)d_in[2];
  const float* dnw = (const float*)d_in[3];
  float* out = (float*)d_out;
  char* ws = (char*)d_ws;

  int* ctrl = (int*)ws;        // 2 KB control block
  int* ntl  = ctrl + 0;        // 1
  int* offs = ctrl + 8;        // 8
  int* de   = ctrl + 16;       // 64
  int* dr0  = ctrl + 80;       // 64
  int* dva  = ctrl + 144;      // 64
  int* ccnt = ctrl + 208;      // 64 chunk_cnt[8][8]
  int* coff = ctrl + 272;      // 64 coff[8][8]

  int*    tok_e  = (int*)  (ws + 2048);          // 4096 ints
  float*  tok_p  = (float*)(ws + 18432);         // 4096 f32
  int*    assign = (int*)  (ws + 34816);         // 4096 ints
  ushort* xg     = (ushort*)(ws + 51200);        // CAPROWS x 1024 bf16
  ushort* hid    = (ushort*)(ws + 8701952ull);   // CAPROWS x 2048 bf16
  int*    rnk    = (int*)   (ws + 8701952ull);   // aliases hid head: dead before gemm_gu
  ushort* gut    = (ushort*)(ws + 26003456ull);  // 8 x 4096 x 1024 bf16
  ushort* dnt    = (ushort*)(ws + 93112320ull);  // 8 x 1024 x 2048 bf16
  // total ws needed: 126,666,752 bytes

  hipMemsetAsync(out, 0, (size_t)NT*DM*4, stream);

  k_router<<<NT/4, 256, 0, stream>>>(x, rw, tok_e, tok_p);
  k_count<<<NT/256, 256, 0, stream>>>(tok_e, rnk, ccnt);
  k_scan<<<1, 64, 0, stream>>>(ccnt, offs, coff, de, dr0, dva, ntl);
  k_gather<<<NT/4, 256, 0, stream>>>(x, tok_e, tok_p, rnk, coff, assign, xg);
  k_transpose<<<dim3(64, 16, 8), 256, 0, stream>>>(guw, gut, 1024, 4096);
  k_transpose<<<dim3(16, 32, 8), 256, 0, stream>>>(dnw, dnt, 2048, 1024);

  k_gemm_gu<<<dim3(32, MAXTILES), 256, 0, stream>>>(xg, gut, hid, de, dr0, dva, ntl);
  k_gemm_dn<<<dim3(16, MAXTILES), 256, 0, stream>>>(hid, dnt, out, de, dr0, dva, ntl, assign);
}

// Round 8
// 406.291 us; speedup vs baseline: 1.0116x; 1.0116x over previous
//
#include <hip/hip_runtime.h>
#include <hip/hip_bf16.h>
#include <stdint.h>

#define NT 2048
#define DM 1024
#define DFF 2048
#define NE 8
#define NASSIGN (NT*2)
#define CAPROWS (NASSIGN+128)
#define MAXTILES 40
#define BK 32   // k-chunk per LDS tile, in ushorts (64B rows)

typedef __attribute__((ext_vector_type(4))) float f32x4;
typedef __attribute__((ext_vector_type(8))) short bf16x8;

// async global->LDS, 16B per lane; LDS dest = wave-uniform base + lane*16
#define GLOAD16(gptr, lptr) __builtin_amdgcn_global_load_lds( \
    (const __attribute__((address_space(1))) void*)(gptr), \
    (__attribute__((address_space(3))) void*)(lptr), 16, 0, 0)

__device__ __forceinline__ ushort f2bf(float f) {
  union { float f; uint32_t u; } v; v.f = f;
  uint32_t u = v.u;
  return (ushort)((u + 0x7FFFu + ((u >> 16) & 1u)) >> 16);
}

// ---------------- router: one wave per token (no atomics) ----------------
__global__ __launch_bounds__(256) void k_router(const float* __restrict__ x,
    const float* __restrict__ rw, int* __restrict__ tok_e, float* __restrict__ tok_p) {
  __shared__ float srw[NE*DM];
  int tid = threadIdx.x;
  #pragma unroll
  for (int i = 0; i < NE*DM/256; i++) srw[tid + i*256] = rw[tid + i*256];
  __syncthreads();
  int lane = tid & 63;
  int t = blockIdx.x*4 + (tid >> 6);
  const float* xr = x + (size_t)t*DM;
  float acc[NE];
  #pragma unroll
  for (int e = 0; e < NE; e++) acc[e] = 0.f;
  for (int i = lane; i < DM; i += 64) {
    float xv = xr[i];
    #pragma unroll
    for (int e = 0; e < NE; e++) acc[e] = fmaf(xv, srw[e*DM + i], acc[e]);
  }
  #pragma unroll
  for (int e = 0; e < NE; e++) {
    float v = acc[e];
    #pragma unroll
    for (int o = 32; o > 0; o >>= 1) v += __shfl_xor(v, o);
    acc[e] = v;
  }
  float mx = acc[0];
  #pragma unroll
  for (int e = 1; e < NE; e++) mx = fmaxf(mx, acc[e]);
  float p[NE]; float s = 0.f;
  #pragma unroll
  for (int e = 0; e < NE; e++) { p[e] = __expf(acc[e]-mx); s += p[e]; }
  int e1 = 0; float b1 = p[0];
  #pragma unroll
  for (int e = 1; e < NE; e++) if (p[e] > b1) { b1 = p[e]; e1 = e; }
  int e2 = -1; float b2 = -1.f;
  #pragma unroll
  for (int e = 0; e < NE; e++) if (e != e1 && p[e] > b2) { b2 = p[e]; e2 = e; }
  if (lane == 0) {
    tok_e[2*t] = e1; tok_e[2*t+1] = e2;
    float inv = 1.f/s;
    tok_p[2*t] = b1*inv; tok_p[2*t+1] = b2*inv;
  }
}

// ---------------- count: deterministic within-chunk ranks, no atomics -------
__global__ __launch_bounds__(256) void k_count(const int* __restrict__ tok_e,
    int* __restrict__ rnk, int* __restrict__ chunk_cnt) {
  __shared__ int wcnt[4][NE];
  __shared__ int woff[4][NE];
  int tid = threadIdx.x, lane = tid & 63, wv = tid >> 6;
  int t = blockIdx.x*256 + tid;
  int e1 = tok_e[2*t], e2 = tok_e[2*t+1];
  unsigned long long lt = (lane == 63) ? 0x7FFFFFFFFFFFFFFFull
                                       : ((1ull << lane) - 1ull);
  int r0 = 0, r1 = 0;
  #pragma unroll
  for (int e = 0; e < NE; e++) {
    unsigned long long m0 = __ballot(e1 == e);
    unsigned long long m1 = __ballot(e2 == e);
    if (e1 == e) r0 = __popcll(m0 & lt) + __popcll(m1 & lt);
    if (e2 == e) r1 = __popcll(m0 & lt) + (int)(e1 == e) + __popcll(m1 & lt);
    if (lane == 0) wcnt[wv][e] = __popcll(m0) + __popcll(m1);
  }
  __syncthreads();
  if (tid < NE) {
    int s = 0;
    #pragma unroll
    for (int w = 0; w < 4; w++) { woff[w][tid] = s; s += wcnt[w][tid]; }
    chunk_cnt[blockIdx.x*NE + tid] = s;
  }
  __syncthreads();
  rnk[2*t]   = woff[wv][e1] + r0;
  rnk[2*t+1] = woff[wv][e2] + r1;
}

// ---------------- scan: expert offsets, chunk offsets, tile descriptors -----
__global__ void k_scan(const int* __restrict__ chunk_cnt, int* __restrict__ offs,
    int* __restrict__ coff, int* __restrict__ d_e, int* __restrict__ d_r0,
    int* __restrict__ d_valid, int* __restrict__ ntiles) {
  if (threadIdx.x == 0 && blockIdx.x == 0) {
    int cnt[NE];
    for (int e = 0; e < NE; e++) {
      int s = 0;
      for (int c = 0; c < 8; c++) s += chunk_cnt[c*NE + e];
      cnt[e] = s;
    }
    int off = 0, nt2 = 0;
    for (int e = 0; e < NE; e++) {
      offs[e] = off;
      int s = off;
      for (int c = 0; c < 8; c++) { coff[c*NE + e] = s; s += chunk_cnt[c*NE + e]; }
      for (int r = 0; r < cnt[e]; r += 128) {
        d_e[nt2] = e; d_r0[nt2] = off + r;
        d_valid[nt2] = (cnt[e] - r < 128) ? (cnt[e] - r) : 128;
        nt2++;
      }
      off += cnt[e];
    }
    *ntiles = nt2;
  }
}

// ---------------- gather: xg[slot] = bf16(p * x[token]), no atomics ---------
__global__ __launch_bounds__(256) void k_gather(const float* __restrict__ x,
    const int* __restrict__ tok_e, const float* __restrict__ tok_p,
    const int* __restrict__ rnk, const int* __restrict__ coff,
    int* __restrict__ assign_token, ushort* __restrict__ xg) {
  int tid = threadIdx.x, lane = tid & 63;
  int t = blockIdx.x*4 + (tid >> 6);
  const float* xr = x + (size_t)t*DM;
  int chunk = t >> 8;
  #pragma unroll
  for (int j = 0; j < 2; j++) {
    int e = tok_e[2*t+j];
    float pp = tok_p[2*t+j];
    int slot = coff[chunk*NE + e] + rnk[2*t+j];
    if (lane == 0) assign_token[slot] = t;
    ushort* dst = xg + (size_t)slot*DM;
    #pragma unroll
    for (int it = 0; it < 2; it++) {
      int c = lane + it*64;
      float4 v0 = *(const float4*)(xr + c*8);
      float4 v1 = *(const float4*)(xr + c*8 + 4);
      uint4 o;
      o.x = (uint32_t)f2bf(v0.x*pp) | ((uint32_t)f2bf(v0.y*pp) << 16);
      o.y = (uint32_t)f2bf(v0.z*pp) | ((uint32_t)f2bf(v0.w*pp) << 16);
      o.z = (uint32_t)f2bf(v1.x*pp) | ((uint32_t)f2bf(v1.y*pp) << 16);
      o.w = (uint32_t)f2bf(v1.z*pp) | ((uint32_t)f2bf(v1.w*pp) << 16);
      *(uint4*)(dst + c*8) = o;
    }
  }
}

// ---------------- transpose: src [E][K][N] f32 -> dst [E][N][K] bf16 --------
__global__ __launch_bounds__(256) void k_transpose(const float* __restrict__ src,
    ushort* __restrict__ dst, int K, int N) {
  __shared__ ushort tl[64][68];
  int e = blockIdx.z;
  const float* s = src + (size_t)e*K*N;
  ushort* d = dst + (size_t)e*N*K;
  int n0 = blockIdx.x*64, k0 = blockIdx.y*64;
  int tid = threadIdx.x;
  int cx = tid & 15, ry = tid >> 4;
  #pragma unroll
  for (int p = 0; p < 4; p++) {
    int k = k0 + ry + p*16;
    float4 v = *(const float4*)(s + (size_t)k*N + n0 + cx*4);
    tl[cx*4+0][ry+p*16] = f2bf(v.x);
    tl[cx*4+1][ry+p*16] = f2bf(v.y);
    tl[cx*4+2][ry+p*16] = f2bf(v.z);
    tl[cx*4+3][ry+p*16] = f2bf(v.w);
  }
  __syncthreads();
  #pragma unroll
  for (int p = 0; p < 4; p++) {
    int n = ry + p*16;
    ushort* dp = d + (size_t)(n0+n)*K + k0 + cx*4;
    uint2 o;
    o.x = (uint32_t)tl[n][cx*4+0] | ((uint32_t)tl[n][cx*4+1] << 16);
    o.y = (uint32_t)tl[n][cx*4+2] | ((uint32_t)tl[n][cx*4+3] << 16);
    *(uint2*)dp = o;
  }
}

// ---- fused gate+up GEMM: 128(M)x64(N), BK=32, gload_lds, XOR swizzle,
//      3-buffer pipeline with counted vmcnt + raw s_barrier (T4) ------------
__global__ __launch_bounds__(256) void k_gemm_gu(
    const ushort* __restrict__ Abuf, const ushort* __restrict__ Bbuf,
    ushort* __restrict__ hidden,
    const int* __restrict__ d_e, const int* __restrict__ d_r0,
    const int* __restrict__ d_valid, const int* __restrict__ ntiles) {
  if (blockIdx.y >= *ntiles) return;
  const int K = DM;
  const int e     = d_e[blockIdx.y];
  const int row0  = d_r0[blockIdx.y];
  const int valid = d_valid[blockIdx.y];
  const int n0 = blockIdx.x * 64;

  __shared__ __align__(16) ushort As [3*128*BK];  // 24KB (3 bufs)
  __shared__ __align__(16) ushort Bgs[3* 64*BK];  // 12KB
  __shared__ __align__(16) ushort Bus[3* 64*BK];  // 12KB

  int tid = threadIdx.x;
  int lane = tid & 63;
  int wv = tid >> 6;
  int wm = wv >> 1, wn = wv & 1;

  const ushort* Ab  = Abuf + (size_t)row0 * K;
  const ushort* Bgb = Bbuf + ((size_t)e*4096 + n0) * K;
  const ushort* Bub = Bbuf + ((size_t)e*4096 + 2048 + n0) * K;

  // staging: phys row = tid>>2, phys chunk = tid&3; source fetches LOGICAL
  // chunk c = (tid&3) ^ ((tid>>3)&3)   (lane-only inverse swizzle)
  int sr  = tid >> 2;
  int sc8 = (((tid & 3) ^ ((tid >> 3) & 3))) * 8;
  const ushort* Ag0 = Ab  + (size_t)sr*K + sc8;
  const ushort* Ag1 = Ab  + (size_t)(sr+64)*K + sc8;
  const ushort* Gg0 = Bgb + (size_t)sr*K + sc8;
  const ushort* Ug0 = Bub + (size_t)sr*K + sc8;

  // 4 loads per wave per stage -> vmcnt counts 4 per stage
#define STAGE_GU(b, kt) do { \
    int _ko = (kt) * BK; \
    GLOAD16(Ag0 + _ko, As  + (b)*4096 + wv*512); \
    GLOAD16(Ag1 + _ko, As  + (b)*4096 + 2048 + wv*512); \
    GLOAD16(Gg0 + _ko, Bgs + (b)*2048 + wv*512); \
    GLOAD16(Ug0 + _ko, Bus + (b)*2048 + wv*512); \
  } while (0)

  f32x4 accg[4][2], accu[4][2];
  f32x4 zz = {0.f, 0.f, 0.f, 0.f};
  #pragma unroll
  for (int mi = 0; mi < 4; mi++)
    #pragma unroll
    for (int ni = 0; ni < 2; ni++) { accg[mi][ni] = zz; accu[mi][ni] = zz; }

  // read side: logical chunk lane>>4 at phys chunk (lane>>4)^((lane>>1)&3)
  int roff = (lane & 15)*BK + ((lane >> 4) ^ ((lane >> 1) & 3))*8;

  const int NK = K / BK;   // 32
  STAGE_GU(0, 0);
  STAGE_GU(1, 1);
  asm volatile("s_waitcnt lgkmcnt(0)" ::: "memory");
  int cb = 0;
  for (int kt = 0; kt < NK; ++kt) {
    if (kt < NK - 1) asm volatile("s_waitcnt vmcnt(4)" ::: "memory");
    else             asm volatile("s_waitcnt vmcnt(0)" ::: "memory");
    __builtin_amdgcn_s_barrier();      // raw: no compiler vmcnt(0) drain
    if (kt + 2 < NK) {
      int sb = cb + 2; if (sb >= 3) sb -= 3;
      STAGE_GU(sb, kt + 2);            // overwrites buf read 2 iters ago: safe
    }
    const ushort* Ap = As  + cb*4096;
    const ushort* Gp = Bgs + cb*2048;
    const ushort* Up = Bus + cb*2048;
    bf16x8 af[4], bg[2], bu[2];
    #pragma unroll
    for (int mi = 0; mi < 4; mi++)
      af[mi] = *(const bf16x8*)(Ap + (wm*64 + mi*16)*BK + roff);
    #pragma unroll
    for (int ni = 0; ni < 2; ni++) {
      bg[ni] = *(const bf16x8*)(Gp + (wn*32 + ni*16)*BK + roff);
      bu[ni] = *(const bf16x8*)(Up + (wn*32 + ni*16)*BK + roff);
    }
    #pragma unroll
    for (int mi = 0; mi < 4; mi++)
      #pragma unroll
      for (int ni = 0; ni < 2; ni++) {
        accg[mi][ni] = __builtin_amdgcn_mfma_f32_16x16x32_bf16(af[mi], bg[ni], accg[mi][ni], 0, 0, 0);
        accu[mi][ni] = __builtin_amdgcn_mfma_f32_16x16x32_bf16(af[mi], bu[ni], accu[mi][ni], 0, 0, 0);
      }
    cb = (cb + 1 == 3) ? 0 : cb + 1;
  }
#undef STAGE_GU

  #pragma unroll
  for (int mi = 0; mi < 4; mi++) {
    #pragma unroll
    for (int r = 0; r < 4; r++) {
      int row_l = wm*64 + mi*16 + (lane>>4)*4 + r;
      if (row_l < valid) {
        #pragma unroll
        for (int ni = 0; ni < 2; ni++) {
          int col = n0 + wn*32 + ni*16 + (lane&15);
          float g = accg[mi][ni][r];
          g = fminf(fmaxf(g, -10.f), 10.f);
          float sg = g / (1.f + __expf(-g));
          float h = sg * accu[mi][ni][r];
          hidden[(size_t)(row0+row_l)*DFF + col] = f2bf(h);
        }
      }
    }
  }
}

// ---- down GEMM: 128(M)x64(N), BK=32, gload_lds, swizzle, 3-buf counted-vmcnt
// out[token] += hidden_tile @ dnt
__global__ __launch_bounds__(256) void k_gemm_dn(
    const ushort* __restrict__ Abuf, const ushort* __restrict__ Bbuf,
    float* __restrict__ out,
    const int* __restrict__ d_e, const int* __restrict__ d_r0,
    const int* __restrict__ d_valid, const int* __restrict__ ntiles,
    const int* __restrict__ assign_token) {
  if (blockIdx.y >= *ntiles) return;
  const int K = DFF;
  const int e     = d_e[blockIdx.y];
  const int row0  = d_r0[blockIdx.y];
  const int valid = d_valid[blockIdx.y];
  const int n0 = blockIdx.x * 64;

  __shared__ __align__(16) ushort As[3*128*BK];  // 24KB
  __shared__ __align__(16) ushort Bs[3* 64*BK];  // 12KB
  __shared__ int toks[128];

  int tid = threadIdx.x;
  int lane = tid & 63;
  int wv = tid >> 6;
  int wm = wv >> 1, wn = wv & 1;

  const ushort* Ab = Abuf + (size_t)row0 * K;
  const ushort* Bb = Bbuf + ((size_t)e*1024 + n0) * K;
  if (tid < 128) toks[tid] = assign_token[row0 + tid];

  int sr  = tid >> 2;
  int sc8 = (((tid & 3) ^ ((tid >> 3) & 3))) * 8;
  const ushort* Ag0 = Ab + (size_t)sr*K + sc8;
  const ushort* Ag1 = Ab + (size_t)(sr+64)*K + sc8;
  const ushort* Bg0 = Bb + (size_t)sr*K + sc8;

  // 3 loads per wave per stage -> vmcnt counts 3 per stage
#define STAGE_DN(b, kt) do { \
    int _ko = (kt) * BK; \
    GLOAD16(Ag0 + _ko, As + (b)*4096 + wv*512); \
    GLOAD16(Ag1 + _ko, As + (b)*4096 + 2048 + wv*512); \
    GLOAD16(Bg0 + _ko, Bs + (b)*2048 + wv*512); \
  } while (0)

  f32x4 acc[4][2];
  f32x4 zz = {0.f, 0.f, 0.f, 0.f};
  #pragma unroll
  for (int mi = 0; mi < 4; mi++)
    #pragma unroll
    for (int ni = 0; ni < 2; ni++) acc[mi][ni] = zz;

  int roff = (lane & 15)*BK + ((lane >> 4) ^ ((lane >> 1) & 3))*8;

  const int NK = K / BK;   // 64
  STAGE_DN(0, 0);
  STAGE_DN(1, 1);
  asm volatile("s_waitcnt lgkmcnt(0)" ::: "memory");   // toks write visible
  int cb = 0;
  for (int kt = 0; kt < NK; ++kt) {
    if (kt < NK - 1) asm volatile("s_waitcnt vmcnt(3)" ::: "memory");
    else             asm volatile("s_waitcnt vmcnt(0)" ::: "memory");
    __builtin_amdgcn_s_barrier();
    if (kt + 2 < NK) {
      int sb = cb + 2; if (sb >= 3) sb -= 3;
      STAGE_DN(sb, kt + 2);
    }
    const ushort* Ap = As + cb*4096;
    const ushort* Bp = Bs + cb*2048;
    bf16x8 af[4], bfr[2];
    #pragma unroll
    for (int mi = 0; mi < 4; mi++)
      af[mi] = *(const bf16x8*)(Ap + (wm*64 + mi*16)*BK + roff);
    #pragma unroll
    for (int ni = 0; ni < 2; ni++)
      bfr[ni] = *(const bf16x8*)(Bp + (wn*32 + ni*16)*BK + roff);
    #pragma unroll
    for (int mi = 0; mi < 4; mi++)
      #pragma unroll
      for (int ni = 0; ni < 2; ni++)
        acc[mi][ni] = __builtin_amdgcn_mfma_f32_16x16x32_bf16(af[mi], bfr[ni], acc[mi][ni], 0, 0, 0);
    cb = (cb + 1 == 3) ? 0 : cb + 1;
  }
#undef STAGE_DN

  #pragma unroll
  for (int mi = 0; mi < 4; mi++) {
    #pragma unroll
    for (int r = 0; r < 4; r++) {
      int row_l = wm*64 + mi*16 + (lane>>4)*4 + r;
      if (row_l < valid) {
        #pragma unroll
        for (int ni = 0; ni < 2; ni++) {
          int col = n0 + wn*32 + ni*16 + (lane&15);
          atomicAdd(out + (size_t)toks[row_l]*DM + col, acc[mi][ni][r]);
        }
      }
    }
  }
}

// ---------------- launch ----------------
extern "C" void kernel_launch(void* const* d_in, const int* in_sizes, int n_in,
                              void* d_out, int out_size, void* d_ws, size_t ws_size,
                              hipStream_t stream) {
  const float* x   = (const float*)d_in[0];
  const float* rw  = (const float*)d_in[1];
  const float* guw = (const float*)d_in[2];
  const float* dnw = (const float*)d_in[3];
  float* out = (float*)d_out;
  char* ws = (char*)d_ws;

  int* ctrl = (int*)ws;        // 2 KB control block
  int* ntl  = ctrl + 0;        // 1
  int* offs = ctrl + 8;        // 8
  int* de   = ctrl + 16;       // 64
  int* dr0  = ctrl + 80;       // 64
  int* dva  = ctrl + 144;      // 64
  int* ccnt = ctrl + 208;      // 64 chunk_cnt[8][8]
  int* coff = ctrl + 272;      // 64 coff[8][8]

  int*    tok_e  = (int*)  (ws + 2048);          // 4096 ints
  float*  tok_p  = (float*)(ws + 18432);         // 4096 f32
  int*    assign = (int*)  (ws + 34816);         // 4096 ints
  ushort* xg     = (ushort*)(ws + 51200);        // CAPROWS x 1024 bf16
  ushort* hid    = (ushort*)(ws + 8701952ull);   // CAPROWS x 2048 bf16
  int*    rnk    = (int*)   (ws + 8701952ull);   // aliases hid head: dead before gemm_gu
  ushort* gut    = (ushort*)(ws + 26003456ull);  // 8 x 4096 x 1024 bf16
  ushort* dnt    = (ushort*)(ws + 93112320ull);  // 8 x 1024 x 2048 bf16
  // total ws needed: 126,666,752 bytes

  hipMemsetAsync(out, 0, (size_t)NT*DM*4, stream);

  k_router<<<NT/4, 256, 0, stream>>>(x, rw, tok_e, tok_p);
  k_count<<<NT/256, 256, 0, stream>>>(tok_e, rnk, ccnt);
  k_scan<<<1, 64, 0, stream>>>(ccnt, offs, coff, de, dr0, dva, ntl);
  k_gather<<<NT/4, 256, 0, stream>>>(x, tok_e, tok_p, rnk, coff, assign, xg);
  k_transpose<<<dim3(64, 16, 8), 256, 0, stream>>>(guw, gut, 1024, 4096);
  k_transpose<<<dim3(16, 32, 8), 256, 0, stream>>>(dnw, dnt, 2048, 1024);

  k_gemm_gu<<<dim3(32, MAXTILES), 256, 0, stream>>>(xg, gut, hid, de, dr0, dva, ntl);
  k_gemm_dn<<<dim3(16, MAXTILES), 256, 0, stream>>>(hid, dnt, out, de, dr0, dva, ntl, assign);
}

// Round 9
// 395.086 us; speedup vs baseline: 1.0403x; 1.0284x over previous
//
#include <hip/hip_runtime.h>
#include <hip/hip_bf16.h>
#include <stdint.h>

#define NT 2048
#define DM 1024
#define DFF 2048
#define NE 8
#define NASSIGN (NT*2)
#define CAPROWS (NASSIGN+128)
#define MAXTILES 40
#define BK 32   // k-chunk per LDS tile, in ushorts (64B rows)

typedef __attribute__((ext_vector_type(4))) float f32x4;
typedef __attribute__((ext_vector_type(8))) short bf16x8;

// async global->LDS, 16B per lane; LDS dest = wave-uniform base + lane*16
#define GLOAD16(gptr, lptr) __builtin_amdgcn_global_load_lds( \
    (const __attribute__((address_space(1))) void*)(gptr), \
    (__attribute__((address_space(3))) void*)(lptr), 16, 0, 0)

__device__ __forceinline__ ushort f2bf(float f) {
  union { float f; uint32_t u; } v; v.f = f;
  uint32_t u = v.u;
  return (ushort)((u + 0x7FFFu + ((u >> 16) & 1u)) >> 16);
}

// ---------------- router: one wave per token (no atomics) ----------------
__global__ __launch_bounds__(256) void k_router(const float* __restrict__ x,
    const float* __restrict__ rw, int* __restrict__ tok_e, float* __restrict__ tok_p) {
  __shared__ float srw[NE*DM];
  int tid = threadIdx.x;
  #pragma unroll
  for (int i = 0; i < NE*DM/256; i++) srw[tid + i*256] = rw[tid + i*256];
  __syncthreads();
  int lane = tid & 63;
  int t = blockIdx.x*4 + (tid >> 6);
  const float* xr = x + (size_t)t*DM;
  float acc[NE];
  #pragma unroll
  for (int e = 0; e < NE; e++) acc[e] = 0.f;
  for (int i = lane; i < DM; i += 64) {
    float xv = xr[i];
    #pragma unroll
    for (int e = 0; e < NE; e++) acc[e] = fmaf(xv, srw[e*DM + i], acc[e]);
  }
  #pragma unroll
  for (int e = 0; e < NE; e++) {
    float v = acc[e];
    #pragma unroll
    for (int o = 32; o > 0; o >>= 1) v += __shfl_xor(v, o);
    acc[e] = v;
  }
  float mx = acc[0];
  #pragma unroll
  for (int e = 1; e < NE; e++) mx = fmaxf(mx, acc[e]);
  float p[NE]; float s = 0.f;
  #pragma unroll
  for (int e = 0; e < NE; e++) { p[e] = __expf(acc[e]-mx); s += p[e]; }
  int e1 = 0; float b1 = p[0];
  #pragma unroll
  for (int e = 1; e < NE; e++) if (p[e] > b1) { b1 = p[e]; e1 = e; }
  int e2 = -1; float b2 = -1.f;
  #pragma unroll
  for (int e = 0; e < NE; e++) if (e != e1 && p[e] > b2) { b2 = p[e]; e2 = e; }
  if (lane == 0) {
    tok_e[2*t] = e1; tok_e[2*t+1] = e2;
    float inv = 1.f/s;
    tok_p[2*t] = b1*inv; tok_p[2*t+1] = b2*inv;
  }
}

// ---------------- count: deterministic within-chunk ranks, no atomics -------
__global__ __launch_bounds__(256) void k_count(const int* __restrict__ tok_e,
    int* __restrict__ rnk, int* __restrict__ chunk_cnt) {
  __shared__ int wcnt[4][NE];
  __shared__ int woff[4][NE];
  int tid = threadIdx.x, lane = tid & 63, wv = tid >> 6;
  int t = blockIdx.x*256 + tid;
  int e1 = tok_e[2*t], e2 = tok_e[2*t+1];
  unsigned long long lt = (lane == 63) ? 0x7FFFFFFFFFFFFFFFull
                                       : ((1ull << lane) - 1ull);
  int r0 = 0, r1 = 0;
  #pragma unroll
  for (int e = 0; e < NE; e++) {
    unsigned long long m0 = __ballot(e1 == e);
    unsigned long long m1 = __ballot(e2 == e);
    if (e1 == e) r0 = __popcll(m0 & lt) + __popcll(m1 & lt);
    if (e2 == e) r1 = __popcll(m0 & lt) + (int)(e1 == e) + __popcll(m1 & lt);
    if (lane == 0) wcnt[wv][e] = __popcll(m0) + __popcll(m1);
  }
  __syncthreads();
  if (tid < NE) {
    int s = 0;
    #pragma unroll
    for (int w = 0; w < 4; w++) { woff[w][tid] = s; s += wcnt[w][tid]; }
    chunk_cnt[blockIdx.x*NE + tid] = s;
  }
  __syncthreads();
  rnk[2*t]   = woff[wv][e1] + r0;
  rnk[2*t+1] = woff[wv][e2] + r1;
}

// ---------------- scan: expert offsets, chunk offsets, tile descriptors -----
__global__ void k_scan(const int* __restrict__ chunk_cnt, int* __restrict__ offs,
    int* __restrict__ coff, int* __restrict__ d_e, int* __restrict__ d_r0,
    int* __restrict__ d_valid, int* __restrict__ ntiles) {
  if (threadIdx.x == 0 && blockIdx.x == 0) {
    int cnt[NE];
    for (int e = 0; e < NE; e++) {
      int s = 0;
      for (int c = 0; c < 8; c++) s += chunk_cnt[c*NE + e];
      cnt[e] = s;
    }
    int off = 0, nt2 = 0;
    for (int e = 0; e < NE; e++) {
      offs[e] = off;
      int s = off;
      for (int c = 0; c < 8; c++) { coff[c*NE + e] = s; s += chunk_cnt[c*NE + e]; }
      for (int r = 0; r < cnt[e]; r += 128) {
        d_e[nt2] = e; d_r0[nt2] = off + r;
        d_valid[nt2] = (cnt[e] - r < 128) ? (cnt[e] - r) : 128;
        nt2++;
      }
      off += cnt[e];
    }
    *ntiles = nt2;
  }
}

// ---------------- gather: xg[slot] = bf16(p * x[token]), no atomics ---------
__global__ __launch_bounds__(256) void k_gather(const float* __restrict__ x,
    const int* __restrict__ tok_e, const float* __restrict__ tok_p,
    const int* __restrict__ rnk, const int* __restrict__ coff,
    int* __restrict__ assign_token, ushort* __restrict__ xg) {
  int tid = threadIdx.x, lane = tid & 63;
  int t = blockIdx.x*4 + (tid >> 6);
  const float* xr = x + (size_t)t*DM;
  int chunk = t >> 8;
  #pragma unroll
  for (int j = 0; j < 2; j++) {
    int e = tok_e[2*t+j];
    float pp = tok_p[2*t+j];
    int slot = coff[chunk*NE + e] + rnk[2*t+j];
    if (lane == 0) assign_token[slot] = t;
    ushort* dst = xg + (size_t)slot*DM;
    #pragma unroll
    for (int it = 0; it < 2; it++) {
      int c = lane + it*64;
      float4 v0 = *(const float4*)(xr + c*8);
      float4 v1 = *(const float4*)(xr + c*8 + 4);
      uint4 o;
      o.x = (uint32_t)f2bf(v0.x*pp) | ((uint32_t)f2bf(v0.y*pp) << 16);
      o.y = (uint32_t)f2bf(v0.z*pp) | ((uint32_t)f2bf(v0.w*pp) << 16);
      o.z = (uint32_t)f2bf(v1.x*pp) | ((uint32_t)f2bf(v1.y*pp) << 16);
      o.w = (uint32_t)f2bf(v1.z*pp) | ((uint32_t)f2bf(v1.w*pp) << 16);
      *(uint4*)(dst + c*8) = o;
    }
  }
}

// ---------------- transpose: src [E][K][N] f32 -> dst [E][N][K] bf16 --------
__global__ __launch_bounds__(256) void k_transpose(const float* __restrict__ src,
    ushort* __restrict__ dst, int K, int N) {
  __shared__ ushort tl[64][68];
  int e = blockIdx.z;
  const float* s = src + (size_t)e*K*N;
  ushort* d = dst + (size_t)e*N*K;
  int n0 = blockIdx.x*64, k0 = blockIdx.y*64;
  int tid = threadIdx.x;
  int cx = tid & 15, ry = tid >> 4;
  #pragma unroll
  for (int p = 0; p < 4; p++) {
    int k = k0 + ry + p*16;
    float4 v = *(const float4*)(s + (size_t)k*N + n0 + cx*4);
    tl[cx*4+0][ry+p*16] = f2bf(v.x);
    tl[cx*4+1][ry+p*16] = f2bf(v.y);
    tl[cx*4+2][ry+p*16] = f2bf(v.z);
    tl[cx*4+3][ry+p*16] = f2bf(v.w);
  }
  __syncthreads();
  #pragma unroll
  for (int p = 0; p < 4; p++) {
    int n = ry + p*16;
    ushort* dp = d + (size_t)(n0+n)*K + k0 + cx*4;
    uint2 o;
    o.x = (uint32_t)tl[n][cx*4+0] | ((uint32_t)tl[n][cx*4+1] << 16);
    o.y = (uint32_t)tl[n][cx*4+2] | ((uint32_t)tl[n][cx*4+3] << 16);
    *(uint2*)dp = o;
  }
}

// ---- fused gate+up GEMM: 128(M)x64(N)x{gate,up}, BK=32, 8 waves (4Mx2N),
//      each wave owns 32x32 of BOTH panels; simple 2-barrier loop,
//      global_load_lds + XOR-swizzled LDS (verified conflict-free) ----------
__global__ __launch_bounds__(512) void k_gemm_gu(
    const ushort* __restrict__ Abuf, const ushort* __restrict__ Bbuf,
    ushort* __restrict__ hidden,
    const int* __restrict__ d_e, const int* __restrict__ d_r0,
    const int* __restrict__ d_valid, const int* __restrict__ ntiles) {
  if (blockIdx.y >= *ntiles) return;
  const int K = DM;
  const int e     = d_e[blockIdx.y];
  const int row0  = d_r0[blockIdx.y];
  const int valid = d_valid[blockIdx.y];
  const int n0 = blockIdx.x * 64;

  __shared__ __align__(16) ushort As[128*BK];  // 8KB  A rows 0..127
  __shared__ __align__(16) ushort Bs[128*BK];  // 8KB  rows 0..63 gate, 64..127 up

  int tid = threadIdx.x;
  int lane = tid & 63;
  int wv = tid >> 6;          // 0..7
  int wm = wv >> 1;           // 0..3 -> M rows wm*32..+31
  int wn = wv & 1;            // 0..1 -> N cols wn*32..+31

  const ushort* Ab  = Abuf + (size_t)row0 * K;
  const ushort* Bgb = Bbuf + ((size_t)e*4096 + n0) * K;
  const ushort* Bub = Bbuf + ((size_t)e*4096 + 2048 + n0) * K;

  // staging: thread t -> phys row t>>2 (0..127), phys chunk t&3;
  // source fetches LOGICAL chunk (t&3) ^ ((t>>3)&3)  (inverse swizzle)
  int sr  = tid >> 2;
  int sc8 = (((tid & 3) ^ ((tid >> 3) & 3))) * 8;
  const ushort* Ag = Ab + (size_t)sr*K + sc8;
  const ushort* Bg = (sr < 64 ? Bgb + (size_t)sr*K
                              : Bub + (size_t)(sr-64)*K) + sc8;
  ushort* Adst = As + wv*512;   // + lane*16B implicit (linear per wave)
  ushort* Bdst = Bs + wv*512;

  f32x4 ag[2][2], au[2][2];
  f32x4 zz = {0.f, 0.f, 0.f, 0.f};
  #pragma unroll
  for (int mi = 0; mi < 2; mi++)
    #pragma unroll
    for (int ni = 0; ni < 2; ni++) { ag[mi][ni] = zz; au[mi][ni] = zz; }

  // read side: logical chunk lane>>4 of row (..+lane&15) at phys chunk
  // (lane>>4) ^ ((lane>>1)&3)
  int roff = (lane & 15)*BK + ((lane >> 4) ^ ((lane >> 1) & 3))*8;

  const int NK = K / BK;   // 32
  for (int kt = 0; kt < NK; kt++) {
    int ko = kt * BK;
    __syncthreads();
    GLOAD16(Ag + ko, Adst);
    GLOAD16(Bg + ko, Bdst);
    __syncthreads();   // compiler drains vmcnt(0) before s_barrier

    bf16x8 af[2], bgf[2], buf[2];
    #pragma unroll
    for (int mi = 0; mi < 2; mi++)
      af[mi] = *(const bf16x8*)(As + (wm*32 + mi*16)*BK + roff);
    #pragma unroll
    for (int ni = 0; ni < 2; ni++) {
      bgf[ni] = *(const bf16x8*)(Bs + (wn*32 + ni*16)*BK + roff);
      buf[ni] = *(const bf16x8*)(Bs + (64 + wn*32 + ni*16)*BK + roff);
    }
    #pragma unroll
    for (int mi = 0; mi < 2; mi++)
      #pragma unroll
      for (int ni = 0; ni < 2; ni++) {
        ag[mi][ni] = __builtin_amdgcn_mfma_f32_16x16x32_bf16(af[mi], bgf[ni], ag[mi][ni], 0, 0, 0);
        au[mi][ni] = __builtin_amdgcn_mfma_f32_16x16x32_bf16(af[mi], buf[ni], au[mi][ni], 0, 0, 0);
      }
  }

  #pragma unroll
  for (int mi = 0; mi < 2; mi++) {
    #pragma unroll
    for (int r = 0; r < 4; r++) {
      int row_l = wm*32 + mi*16 + (lane>>4)*4 + r;
      if (row_l < valid) {
        #pragma unroll
        for (int ni = 0; ni < 2; ni++) {
          int col = n0 + wn*32 + ni*16 + (lane&15);
          float g = ag[mi][ni][r];
          g = fminf(fmaxf(g, -10.f), 10.f);
          float sg = g / (1.f + __expf(-g));
          float h = sg * au[mi][ni][r];
          hidden[(size_t)(row0+row_l)*DFF + col] = f2bf(h);
        }
      }
    }
  }
}

// ---- down GEMM: 128(M)x64(N), BK=32, 8 waves (4Mx2N, 32x32 each),
//      simple 2-barrier loop, gload_lds + XOR swizzle ------------------------
// out[token] += hidden_tile @ dnt
__global__ __launch_bounds__(512) void k_gemm_dn(
    const ushort* __restrict__ Abuf, const ushort* __restrict__ Bbuf,
    float* __restrict__ out,
    const int* __restrict__ d_e, const int* __restrict__ d_r0,
    const int* __restrict__ d_valid, const int* __restrict__ ntiles,
    const int* __restrict__ assign_token) {
  if (blockIdx.y >= *ntiles) return;
  const int K = DFF;
  const int e     = d_e[blockIdx.y];
  const int row0  = d_r0[blockIdx.y];
  const int valid = d_valid[blockIdx.y];
  const int n0 = blockIdx.x * 64;

  __shared__ __align__(16) ushort As[128*BK];  // 8KB
  __shared__ __align__(16) ushort Bs[ 64*BK];  // 4KB
  __shared__ int toks[128];

  int tid = threadIdx.x;
  int lane = tid & 63;
  int wv = tid >> 6;
  int wm = wv >> 1;           // 0..3
  int wn = wv & 1;            // 0..1

  const ushort* Ab = Abuf + (size_t)row0 * K;
  const ushort* Bb = Bbuf + ((size_t)e*1024 + n0) * K;
  if (tid < 128) toks[tid] = assign_token[row0 + tid];

  int sr  = tid >> 2;
  int sc8 = (((tid & 3) ^ ((tid >> 3) & 3))) * 8;
  const ushort* Ag = Ab + (size_t)sr*K + sc8;
  const ushort* Bg = Bb + (size_t)sr*K + sc8;   // only tid<256 uses
  ushort* Adst = As + wv*512;
  ushort* Bdst = Bs + wv*512;                   // only waves 0..3

  f32x4 acc[2][2];
  f32x4 zz = {0.f, 0.f, 0.f, 0.f};
  #pragma unroll
  for (int mi = 0; mi < 2; mi++)
    #pragma unroll
    for (int ni = 0; ni < 2; ni++) acc[mi][ni] = zz;

  int roff = (lane & 15)*BK + ((lane >> 4) ^ ((lane >> 1) & 3))*8;

  const int NK = K / BK;   // 64
  for (int kt = 0; kt < NK; kt++) {
    int ko = kt * BK;
    __syncthreads();
    GLOAD16(Ag + ko, Adst);
    if (tid < 256) GLOAD16(Bg + ko, Bdst);
    __syncthreads();

    bf16x8 af[2], bf2[2];
    #pragma unroll
    for (int mi = 0; mi < 2; mi++)
      af[mi] = *(const bf16x8*)(As + (wm*32 + mi*16)*BK + roff);
    #pragma unroll
    for (int ni = 0; ni < 2; ni++)
      bf2[ni] = *(const bf16x8*)(Bs + (wn*32 + ni*16)*BK + roff);
    #pragma unroll
    for (int mi = 0; mi < 2; mi++)
      #pragma unroll
      for (int ni = 0; ni < 2; ni++)
        acc[mi][ni] = __builtin_amdgcn_mfma_f32_16x16x32_bf16(af[mi], bf2[ni], acc[mi][ni], 0, 0, 0);
  }

  #pragma unroll
  for (int mi = 0; mi < 2; mi++) {
    #pragma unroll
    for (int r = 0; r < 4; r++) {
      int row_l = wm*32 + mi*16 + (lane>>4)*4 + r;
      if (row_l < valid) {
        #pragma unroll
        for (int ni = 0; ni < 2; ni++) {
          int col = n0 + wn*32 + ni*16 + (lane&15);
          atomicAdd(out + (size_t)toks[row_l]*DM + col, acc[mi][ni][r]);
        }
      }
    }
  }
}

// ---------------- launch ----------------
extern "C" void kernel_launch(void* const* d_in, const int* in_sizes, int n_in,
                              void* d_out, int out_size, void* d_ws, size_t ws_size,
                              hipStream_t stream) {
  const float* x   = (const float*)d_in[0];
  const float* rw  = (const float*)d_in[1];
  const float* guw = (const float*)d_in[2];
  const float* dnw = (const float*)d_in[3];
  float* out = (float*)d_out;
  char* ws = (char*)d_ws;

  int* ctrl = (int*)ws;        // 2 KB control block
  int* ntl  = ctrl + 0;        // 1
  int* offs = ctrl + 8;        // 8
  int* de   = ctrl + 16;       // 64
  int* dr0  = ctrl + 80;       // 64
  int* dva  = ctrl + 144;      // 64
  int* ccnt = ctrl + 208;      // 64 chunk_cnt[8][8]
  int* coff = ctrl + 272;      // 64 coff[8][8]

  int*    tok_e  = (int*)  (ws + 2048);          // 4096 ints
  float*  tok_p  = (float*)(ws + 18432);         // 4096 f32
  int*    assign = (int*)  (ws + 34816);         // 4096 ints
  ushort* xg     = (ushort*)(ws + 51200);        // CAPROWS x 1024 bf16
  ushort* hid    = (ushort*)(ws + 8701952ull);   // CAPROWS x 2048 bf16
  int*    rnk    = (int*)   (ws + 8701952ull);   // aliases hid head: dead before gemm_gu
  ushort* gut    = (ushort*)(ws + 26003456ull);  // 8 x 4096 x 1024 bf16
  ushort* dnt    = (ushort*)(ws + 93112320ull);  // 8 x 1024 x 2048 bf16
  // total ws needed: 126,666,752 bytes

  hipMemsetAsync(out, 0, (size_t)NT*DM*4, stream);

  k_router<<<NT/4, 256, 0, stream>>>(x, rw, tok_e, tok_p);
  k_count<<<NT/256, 256, 0, stream>>>(tok_e, rnk, ccnt);
  k_scan<<<1, 64, 0, stream>>>(ccnt, offs, coff, de, dr0, dva, ntl);
  k_gather<<<NT/4, 256, 0, stream>>>(x, tok_e, tok_p, rnk, coff, assign, xg);
  k_transpose<<<dim3(64, 16, 8), 256, 0, stream>>>(guw, gut, 1024, 4096);
  k_transpose<<<dim3(16, 32, 8), 256, 0, stream>>>(dnw, dnt, 2048, 1024);

  k_gemm_gu<<<dim3(32, MAXTILES), 512, 0, stream>>>(xg, gut, hid, de, dr0, dva, ntl);
  k_gemm_dn<<<dim3(16, MAXTILES), 512, 0, stream>>>(hid, dnt, out, de, dr0, dva, ntl, assign);
}